// Round 5
// baseline (30.050 us; speedup 1.0000x reference)
//
#include <hip/hip_runtime.h>
#include <hip/hip_bf16.h>

// FilterbankLinear: out[b, j*8+o] = sum_{c,t} x[b,c,s_j+t] * w[j*8+o, c*32+t]
// s_j = j (j<4063), s_4063 = 4064.
// Block = 8 windows, 8 WAVES (512 thr) -- one window per wave, both 16-batch
// M-tiles. Grid 508, ~2 blocks/CU -> 16 waves/CU (50% occupancy).
// x: LDS fp32 stage via global_load_lds dwordx4, triple-buffered, depth-2
// prefetch, counted vmcnt + raw s_barrier. w: float4 register prefetch.

#define NF 4096
#define NC 21
#define WIN 32
#define OC 8
#define NWIN 4064
#define NKTOT (OC * NWIN)
#define DD (NC * WIN)       // 672
#define JB 8
#define NBLK (NWIN / JB)    // 508
#define XROWB 272           // 17 chunks * 16B per x row in LDS
#define XBUFB 9216          // 576 chunks * 16B per buffer

typedef short short8 __attribute__((ext_vector_type(8)));
typedef float f32x4 __attribute__((ext_vector_type(4)));

static __device__ __forceinline__ short f2bf(float f) {
  __bf16 h = (__bf16)f;
  return __builtin_bit_cast(short, h);
}
static __device__ __forceinline__ short8 pk8(float a, float b, float c, float d,
                                             float e, float f, float g, float h) {
  short8 v;
  v[0]=f2bf(a); v[1]=f2bf(b); v[2]=f2bf(c); v[3]=f2bf(d);
  v[4]=f2bf(e); v[5]=f2bf(f); v[6]=f2bf(g); v[7]=f2bf(h);
  return v;
}
// select 8 consecutive floats out of 12 by wave-uniform u (static indices only)
static __device__ __forceinline__ short8 sel8(f32x4 a, f32x4 b, f32x4 c, int u) {
  switch (u & 3) {
    case 0:  return pk8(a[0],a[1],a[2],a[3],b[0],b[1],b[2],b[3]);
    case 1:  return pk8(a[1],a[2],a[3],b[0],b[1],b[2],b[3],c[0]);
    case 2:  return pk8(a[2],a[3],b[0],b[1],b[2],b[3],c[0],c[1]);
    default: return pk8(a[3],b[0],b[1],b[2],b[3],c[0],c[1],c[2]);
  }
}

// counted vmcnt wait, compile-time immediates (never 0 in the main loop)
static __device__ __forceinline__ void wait_vmcnt(int n) {
  switch (n) {
    case 2: asm volatile("s_waitcnt vmcnt(2)" ::: "memory"); break;
    case 3: asm volatile("s_waitcnt vmcnt(3)" ::: "memory"); break;
    default: asm volatile("s_waitcnt vmcnt(4)" ::: "memory"); break;
  }
}

#define STAGE(GP, I, NB) \
  __builtin_amdgcn_global_load_lds( \
    (const __attribute__((address_space(1))) unsigned int*)(GP), \
    (__attribute__((address_space(3))) unsigned int*)(xlds + (NB)*XBUFB + (I)*1024), \
    16, 0, 0)

__global__ __launch_bounds__(512) void fb_pipe8(const float* __restrict__ x,
                                                const float* __restrict__ w,
                                                float* __restrict__ out) {
  __shared__ __align__(16) char xlds[3 * XBUFB];
  const int lane = threadIdx.x & 63;
  const int wv   = threadIdx.x >> 6;          // 0..7

  // bijective XCD swizzle (nwg=508: q=63, r=4)
  const int orig = blockIdx.x;
  const int xcd = orig & 7, idx = orig >> 3;
  const int blk = (xcd < 4 ? xcd * 64 : 256 + (xcd - 4) * 63) + idx;
  const int j0 = blk * JB;
  const int a0 = (j0 < NF - 68) ? j0 : (NF - 68);   // staged span base

  const int n  = lane & 15;
  const int o  = n & 7;
  const int Ck = (lane >> 4) * 2;
  const int boff0 = n * XROWB, boff1 = (16 + n) * XROWB;

  // this wave's window
  const int jg = j0 + wv;
  const int sv = (jg == NWIN - 1) ? (NF - WIN) : jg;
  const int rj = sv - a0;
  const int u  = rj & 3;
  const int Cw = rj >> 2;

  // staging coords: wave wv writes chunks wv*64+lane; wave 0 also 512+lane
  int q0 = wv * 64 + lane;
  int q2 = 512 + lane;
  if (q2 > 543) q2 = 543;                 // clamp: dup-writes land in pad
  const int b0 = q0 / 17, p0 = q0 - b0 * 17;
  const int b2 = q2 / 17, p2 = q2 - b2 * 17;
  const float* xs0 = x + (size_t)b0 * (NC * NF) + a0 + p0 * 4;
  const float* xs2 = x + (size_t)b2 * (NC * NF) + a0 + p2 * 4;

  const float* wn = w + ((size_t)jg * OC + o) * DD + Ck * 4;

  f32x4 acc0 = {0,0,0,0}, acc1 = {0,0,0,0};

  // ---- prologue: stage ch0->B0, ch1->B1; load w(ch0) ----
  STAGE(xs0, wv, 0);
  if (wv == 0) { STAGE(xs2, 8, 0); }
  xs0 += NF; xs2 += NF;
  STAGE(xs0, wv, 1);
  if (wv == 0) { STAGE(xs2, 8, 1); }
  xs0 += NF; xs2 += NF;
  float4 wa = *(const float4*)(wn), wb = *(const float4*)(wn + 4);
  wn += WIN;

  const int STN = (wv == 0) ? 2 : 1;      // stage ops per wave per channel

  #pragma unroll
  for (int c = 0; c < NC; ++c) {
    // need stage(c) complete; stage(c+1) [SIN] + w(c) [2] stay in flight
    if (c < NC - 1) wait_vmcnt(STN + 2);
    else            wait_vmcnt(2);
    __builtin_amdgcn_s_barrier();
    __builtin_amdgcn_sched_barrier(0);

    if (c + 2 < NC) {                     // stage channel c+2 into B[(c+2)%3]
      const int nb = (c + 2) % 3;
      STAGE(xs0, wv, nb);
      if (wv == 0) { STAGE(xs2, 8, nb); }
      xs0 += NF; xs2 += NF;
    }
    float4 wan = {0,0,0,0}, wbn = {0,0,0,0};
    if (c + 1 < NC) {                     // w prefetch for c+1
      wan = *(const float4*)(wn); wbn = *(const float4*)(wn + 4);
      wn += WIN;
    }

    const char* xb = xlds + (c % 3) * XBUFB;
    short8 fbw = pk8(wa.x, wa.y, wa.z, wa.w, wb.x, wb.y, wb.z, wb.w);
    {   // M-tile 0 (batches 0-15)
      int off = boff0 + (Cw + Ck) * 16;
      f32x4 ra = *(const f32x4*)(xb + off);
      f32x4 rb = *(const f32x4*)(xb + off + 16);
      f32x4 rc = *(const f32x4*)(xb + off + 32);
      acc0 = __builtin_amdgcn_mfma_f32_16x16x32_bf16(sel8(ra,rb,rc,u), fbw, acc0, 0,0,0);
    }
    {   // M-tile 1 (batches 16-31)
      int off = boff1 + (Cw + Ck) * 16;
      f32x4 ra = *(const f32x4*)(xb + off);
      f32x4 rb = *(const f32x4*)(xb + off + 16);
      f32x4 rc = *(const f32x4*)(xb + off + 32);
      acc1 = __builtin_amdgcn_mfma_f32_16x16x32_bf16(sel8(ra,rb,rc,u), fbw, acc1, 0,0,0);
    }
    wa = wan; wb = wbn;
  }

  if (n < 8) {
    const int m0 = (lane >> 4) * 4;
    #pragma unroll
    for (int e = 0; e < 4; ++e) {
      out[(size_t)(m0 + e)      * NKTOT + (size_t)jg * OC + n] = acc0[e];
      out[(size_t)(m0 + e + 16) * NKTOT + (size_t)jg * OC + n] = acc1[e];
    }
  }
}

extern "C" void kernel_launch(void* const* d_in, const int* in_sizes, int n_in,
                              void* d_out, int out_size, void* d_ws, size_t ws_size,
                              hipStream_t stream) {
  const float* x = (const float*)d_in[0];
  const float* w = (const float*)d_in[1];
  float* out = (float*)d_out;
  dim3 grid(NBLK), block(512);
  hipLaunchKernelGGL(fb_pipe8, grid, block, 0, stream, x, w, out);
}